// Round 6
// baseline (179.308 us; speedup 1.0000x reference)
//
#include <hip/hip_runtime.h>
#include <math.h>

#define TOPK 4

// Register-prefetch direct-read: no LDS, no barriers, no phase convoy.
// Each lane owns one node and walks its segment in 32-float (2 cache-line)
// batches: issue 8 independent float4 loads back-to-back, then run the masked
// insert chain. Compiler's incremental vmcnt overlaps loads with inserts;
// variable segment lengths desynchronize waves (no chip-wide phase lock).
__global__ __launch_bounds__(256) void segment_top4_kernel(
    const int* __restrict__ row_ptr,
    const float* __restrict__ scores,
    float* __restrict__ vals_out,   // [N,4] float32
    float* __restrict__ idx_out,    // [N,4] indices written as float32
    int n_nodes, int n_edges)
{
    int node = blockIdx.x * blockDim.x + threadIdx.x;
    if (node >= n_nodes) return;

    int seg_beg = row_ptr[node];
    int seg_end = row_ptr[node + 1];

    float v0 = -INFINITY, v1 = -INFINITY, v2 = -INFINITY, v3 = -INFINITY;
    int   i0 = -1, i1 = -1, i2 = -1, i3 = -1;

    // Branchless insertion, strict '>' keeps the smaller edge index on ties
    // (matches reference). sc = -inf never inserts.
    auto ins = [&](float sc, int id) {
        bool g0 = sc > v0, g1 = sc > v1, g2 = sc > v2, g3 = sc > v3;
        v3 = g3 ? (g2 ? v2 : sc) : v3;  i3 = g3 ? (g2 ? i2 : id) : i3;
        v2 = g2 ? (g1 ? v1 : sc) : v2;  i2 = g2 ? (g1 ? i1 : id) : i2;
        v1 = g1 ? (g0 ? v0 : sc) : v1;  i1 = g1 ? (g0 ? i0 : id) : i1;
        v0 = g0 ? sc : v0;              i0 = g0 ? id : i0;
    };

    int clamp_hi = n_edges - 4;   // E % 16 == 0, segments non-empty => >= 0

    // Line-aligned start; 32 floats (2 lines) per batch. Mean segment = 32
    // edges -> ~1.5 batches; most lanes finish in 1-2 iterations.
    for (int base = seg_beg & ~15; base < seg_end; base += 32) {
        float f[32];
        // 8 independent float4 loads, issued back-to-back. Clamp each source
        // in-bounds: any element whose source was clamped has nominal index
        // e = base+4g+j >= n_edges >= seg_end, so the mask below kills it.
        #pragma unroll
        for (int g = 0; g < 8; ++g) {
            int src = base + 4 * g;
            src = src < clamp_hi ? src : clamp_hi;
            float4 q = *(const float4*)(scores + src);
            f[4 * g]     = q.x;
            f[4 * g + 1] = q.y;
            f[4 * g + 2] = q.z;
            f[4 * g + 3] = q.w;
        }
        #pragma unroll
        for (int j = 0; j < 32; ++j) {
            int e = base + j;
            bool in_seg = (e >= seg_beg) & (e < seg_end);
            ins(in_seg ? f[j] : -INFINITY, e);
        }
    }

    float4 vout = make_float4(v0, v1, v2, v3);
    *(float4*)(vals_out + (size_t)node * 4) = vout;
    float4 iout = make_float4((float)i0, (float)i1, (float)i2, (float)i3);
    *(float4*)(idx_out + (size_t)node * 4) = iout;
}

extern "C" void kernel_launch(void* const* d_in, const int* in_sizes, int n_in,
                              void* d_out, int out_size, void* d_ws, size_t ws_size,
                              hipStream_t stream)
{
    const int*   row_ptr = (const int*)d_in[0];
    const float* scores  = (const float*)d_in[1];
    int n_nodes = in_sizes[0] - 1;
    int n_edges = in_sizes[1];

    float* out      = (float*)d_out;
    float* vals_out = out;                           // first N*4 floats
    float* idx_out  = out + (size_t)n_nodes * TOPK;  // next N*4 floats (idx as f32)

    int threads = 256;
    int blocks  = (n_nodes + threads - 1) / threads;
    segment_top4_kernel<<<blocks, threads, 0, stream>>>(
        row_ptr, scores, vals_out, idx_out, n_nodes, n_edges);
}